// Round 3
// 356.165 us; speedup vs baseline: 1.0437x; 1.0437x over previous
//
#include <hip/hip_runtime.h>

#define ADAM_B1 0.9f
#define ADAM_B2 0.999f
#define ADAM_LR 1e-3f
#define ADAM_EPS 1e-8f

// clang-native 16B vector: required by __builtin_nontemporal_load/store
// (HIP's float4 is a class type the builtin rejects).
typedef float f32x4 __attribute__((ext_vector_type(4)));

// K1: one thread per occurrence. Build per-row linked list of occurrences:
//   next[occ] = atomicExch(&head[row], occ)
// head[] must be -1-initialized (memset 0xFF) before this kernel.
__global__ void k_build_list(const int* __restrict__ idx, int* __restrict__ head,
                             int* __restrict__ next_, int n_idx) {
    int i = blockIdx.x * blockDim.x + threadIdx.x;
    if (i >= n_idx) return;
    int row = idx[i];
    next_[i] = atomicExch(&head[row], i);
}

// K2: fused sparse Adam. One half-wave (32 lanes) per table row, f32x4/lane.
//
// Latency fix vs baseline: the emb load and head load issue CONCURRENTLY,
// and the copy-store issues as soon as emb arrives -- BEFORE the
// touched/untouched branch resolves. Untouched rows (77%) thus pay ONE
// memory latency instead of two serialized ones. Touched rows issue a
// second store to the same address; per-thread program order guarantees
// the Adam result wins, and write-back L2 absorbs the duplicate HBM write.
//
// Non-temporal hints on all single-use streams (emb/out/mem/pow/grad)
// keep L2 available for head[]/next_[] chain walks.
__global__ __launch_bounds__(256) void k_adam_fused(
        const float* __restrict__ emb,
        const float* __restrict__ step_,
        const float* __restrict__ mem_,
        const float* __restrict__ pow_,
        const float* __restrict__ grad,
        const int* __restrict__ head,
        const int* __restrict__ next_,
        float* __restrict__ out, int n_emb, int D) {
    int gid = blockIdx.x * blockDim.x + threadIdx.x;
    int row = gid >> 5;                 // one half-wave per row
    int lane = threadIdx.x & 31;
    if (row >= n_emb) return;
    long long base = (long long)row * D;
    const f32x4* e4 = (const f32x4*)(emb + base);
    const f32x4* m4 = (const f32x4*)(mem_ + base);
    const f32x4* p4 = (const f32x4*)(pow_ + base);
    f32x4* o4 = (f32x4*)(out + base);
    int nv = D >> 2;                    // f32x4s per row (32 for D=128)

    int h = head[row];                  // issue now; resolves while copy streams

    for (int c = lane; c < nv; c += 32) {
        // --- unconditional copy: store depends only on the emb load ---
        f32x4 e = __builtin_nontemporal_load(e4 + c);
        __builtin_nontemporal_store(e, o4 + c);

        if (h < 0) continue;            // untouched row: done (1 latency paid)

        // --- touched row: chain-walk grads, Adam update, second store wins ---
        float stepn = step_[row] + 1.0f;
        f32x4 m  = __builtin_nontemporal_load(m4 + c);
        f32x4 pv = __builtin_nontemporal_load(p4 + c);

        f32x4 g = (f32x4)(0.0f);
        float k = 0.0f;
        int p = h;
        while (p >= 0) {
            const f32x4* g4 = (const f32x4*)(grad + (long long)p * D);
            f32x4 gv = __builtin_nontemporal_load(g4 + c);
            g += gv;
            k += 1.0f;
            p = next_[p];
        }

        float inv_cnt = 1.0f / k;
        g *= inv_cnt;

        // pow(b, s) = exp2(s * log2(b)) -- single v_exp_f32 each
        const float L2B1 = -0.15200309344504997f;     // log2(0.9)
        const float L2B2 = -0.0014434592066161948f;   // log2(0.999)
        float d1 = 1.0f - exp2f(stepn * L2B1);
        float d2 = 1.0f - exp2f(stepn * L2B2);
        float inv_d1 = 1.0f / d1;
        float inv_d2 = 1.0f / d2;

        f32x4 r;
        {
            float mx = ADAM_B1 * m.x + (1.0f - ADAM_B1) * g.x;
            float px = ADAM_B2 * pv.x + (1.0f - ADAM_B2) * g.x * g.x;
            r.x = e.x - ADAM_LR * (mx * inv_d1) / (sqrtf(px * inv_d2) + ADAM_EPS);
            float my = ADAM_B1 * m.y + (1.0f - ADAM_B1) * g.y;
            float py = ADAM_B2 * pv.y + (1.0f - ADAM_B2) * g.y * g.y;
            r.y = e.y - ADAM_LR * (my * inv_d1) / (sqrtf(py * inv_d2) + ADAM_EPS);
            float mz = ADAM_B1 * m.z + (1.0f - ADAM_B1) * g.z;
            float pz = ADAM_B2 * pv.z + (1.0f - ADAM_B2) * g.z * g.z;
            r.z = e.z - ADAM_LR * (mz * inv_d1) / (sqrtf(pz * inv_d2) + ADAM_EPS);
            float mw = ADAM_B1 * m.w + (1.0f - ADAM_B1) * g.w;
            float pw = ADAM_B2 * pv.w + (1.0f - ADAM_B2) * g.w * g.w;
            r.w = e.w - ADAM_LR * (mw * inv_d1) / (sqrtf(pw * inv_d2) + ADAM_EPS);
        }
        __builtin_nontemporal_store(r, o4 + c);
    }
}

extern "C" void kernel_launch(void* const* d_in, const int* in_sizes, int n_in,
                              void* d_out, int out_size, void* d_ws, size_t ws_size,
                              hipStream_t stream) {
    const int*   idx   = (const int*)d_in[0];
    const float* grad  = (const float*)d_in[1];
    const float* emb   = (const float*)d_in[2];
    const float* step_ = (const float*)d_in[3];
    const float* mem_  = (const float*)d_in[4];
    const float* pow_  = (const float*)d_in[5];
    float* out = (float*)d_out;

    int n_idx = in_sizes[0];
    int n_emb = in_sizes[3];               // state_step is [N_EMB]
    int D     = in_sizes[1] / n_idx;       // 128

    int* head  = (int*)d_ws;               // n_emb ints
    int* next_ = head + n_emb;             // n_idx ints

    (void)hipMemsetAsync(head, 0xFF, (size_t)n_emb * sizeof(int), stream);  // all -1

    const int blk = 256;
    k_build_list<<<(n_idx + blk - 1) / blk, blk, 0, stream>>>(idx, head, next_, n_idx);

    long long threads = (long long)n_emb * 32;   // one half-wave per row
    k_adam_fused<<<(int)((threads + blk - 1) / blk), blk, 0, stream>>>(
        emb, step_, mem_, pow_, grad, head, next_, out, n_emb, D);
}